// Round 4
// baseline (499.061 us; speedup 1.0000x reference)
//
#include <hip/hip_runtime.h>

#define NB 4096   // B
#define NS 200    // S
#define NP 8      // P
#define NF 64     // F

#define RB 5      // batch rows per block
#define LPS 50    // lane-slices per row (RB*LPS = 250 active threads)

__global__ __launch_bounds__(256) void cf_kernel(
    const int*   __restrict__ user,
    const int*   __restrict__ items,
    const float* __restrict__ user_factors,   // [N_USERS][P][F] fp32
    const float* __restrict__ item_factors,   // [N_ITEMS][F]    fp32
    float* __restrict__ out_pred,             // [B][S]          fp32
    float* __restrict__ out_scores)           // [B][S][P]       fp32
{
    // per-row u, transposed [f][p]: 8 personas of one f = 2 consecutive float4
    __shared__ float u_lds[RB][NF * NP];      // 10 KB

    const int tid  = threadIdx.x;
    const int b0   = blockIdx.x * RB;
    const int rows = min(RB, NB - b0);

    // ---- stage user factors: rows*512 floats, coalesced read, transposed write ----
    for (int e = tid; e < rows * (NP * NF); e += 256) {
        int g = e >> 9;            // /512
        int q = e & 511;
        int uid = user[b0 + g];
        float w = user_factors[(size_t)uid * (NP * NF) + q];
        int p = q >> 6, f = q & 63;
        u_lds[g][f * NP + p] = w;
    }
    __syncthreads();

    const int g = tid / LPS;
    const int l = tid - g * LPS;
    if (g >= rows) return;         // also kills tid 250..255
    const int b = b0 + g;
    const float* __restrict__ ug = u_lds[g];

    // two phases; each phase: load 2 full item rows into registers (each 128B
    // L2 line fetched exactly once, all 16B requests concurrent), then sweep u.
    #pragma unroll
    for (int half = 0; half < 2; ++half) {
        const int s0 = l + LPS * (2 * half);
        const int s1 = s0 + LPS;
        const int i0 = items[b * NS + s0];
        const int i1 = items[b * NS + s1];
        const float4* p0 = (const float4*)(item_factors + (size_t)i0 * NF);
        const float4* p1 = (const float4*)(item_factors + (size_t)i1 * NF);

        float4 v0[16], v1[16];     // whole rows in registers: 32 loads in flight
        #pragma unroll
        for (int i = 0; i < 16; ++i) v0[i] = p0[i];
        #pragma unroll
        for (int i = 0; i < 16; ++i) v1[i] = p1[i];

        float a0[NP], a1[NP];
        #pragma unroll
        for (int p = 0; p < NP; ++p) { a0[p] = 0.f; a1[p] = 0.f; }

        #pragma unroll
        for (int c = 0; c < 8; ++c) {
            #pragma unroll
            for (int j = 0; j < 8; ++j) {
                // <=2 distinct addresses per wave (2 u-tables) -> conflict-free
                const float4* up = (const float4*)&ug[(c * 8 + j) * NP];
                float4 ua = up[0];
                float4 ub = up[1];
                float x0 = ((const float*)&v0[2 * c])[j];   // folds at compile time
                float x1 = ((const float*)&v1[2 * c])[j];
                a0[0] += x0 * ua.x;  a0[1] += x0 * ua.y;
                a0[2] += x0 * ua.z;  a0[3] += x0 * ua.w;
                a0[4] += x0 * ub.x;  a0[5] += x0 * ub.y;
                a0[6] += x0 * ub.z;  a0[7] += x0 * ub.w;
                a1[0] += x1 * ua.x;  a1[1] += x1 * ua.y;
                a1[2] += x1 * ua.z;  a1[3] += x1 * ua.w;
                a1[4] += x1 * ub.x;  a1[5] += x1 * ub.y;
                a1[6] += x1 * ub.z;  a1[7] += x1 * ub.w;
            }
        }

        // ---- softmax + pred + store for both rows ----
        #pragma unroll
        for (int which = 0; which < 2; ++which) {
            float* a = which ? a1 : a0;
            const int s = which ? s1 : s0;
            float m = a[0];
            #pragma unroll
            for (int p = 1; p < NP; ++p) m = fmaxf(m, a[p]);
            float e[NP], sum = 0.f;
            #pragma unroll
            for (int p = 0; p < NP; ++p) { e[p] = __expf(a[p] - m); sum += e[p]; }
            float inv = 1.f / sum;

            float sc[NP], pred = 0.f;
            #pragma unroll
            for (int p = 0; p < NP; ++p) {
                sc[p] = e[p] * inv;
                pred += sc[p] * a[p];
            }

            out_pred[b * NS + s] = pred;
            float4* op = (float4*)(out_scores + (size_t)(b * NS + s) * NP);
            op[0] = make_float4(sc[0], sc[1], sc[2], sc[3]);
            op[1] = make_float4(sc[4], sc[5], sc[6], sc[7]);
        }
    }
}

extern "C" void kernel_launch(void* const* d_in, const int* in_sizes, int n_in,
                              void* d_out, int out_size, void* d_ws, size_t ws_size,
                              hipStream_t stream) {
    const int*   user         = (const int*)d_in[0];
    const int*   items        = (const int*)d_in[1];
    const float* user_factors = (const float*)d_in[2];
    const float* item_factors = (const float*)d_in[3];

    float* out_pred   = (float*)d_out;
    float* out_scores = out_pred + (size_t)NB * NS;   // outputs concatenated: pred, scores

    const int grid = (NB + RB - 1) / RB;   // 820
    cf_kernel<<<grid, 256, 0, stream>>>(user, items, user_factors, item_factors,
                                        out_pred, out_scores);
}